// Round 3
// baseline (1180.749 us; speedup 1.0000x reference)
//
#include <hip/hip_runtime.h>

#define H4 128     // hidden
#define EE 768     // embedding
#define NL 20      // layers
#define BB 64      // batch
#define TT 512     // seq len
#define G4 512     // 4*H
#define NBG 8      // batch groups
#define CK 16      // timesteps per chunk (handoff granularity)
#define NCH (TT/CK)
#define RC 2       // ring slots (chunks) per flow

typedef _Float16 v8h __attribute__((ext_vector_type(8)));
typedef _Float16 v4h __attribute__((ext_vector_type(4)));
typedef float v4f __attribute__((ext_vector_type(4)));
typedef unsigned int v4u __attribute__((ext_vector_type(4)));

#if defined(__has_builtin)
#if __has_builtin(__builtin_amdgcn_exp2f) && __has_builtin(__builtin_amdgcn_rcpf)
#define EXP2F __builtin_amdgcn_exp2f
#define RCPF  __builtin_amdgcn_rcpf
#endif
#endif
#ifndef EXP2F
#define EXP2F exp2f
#define RCPF(x) (1.0f/(x))
#endif

__device__ __forceinline__ float fast_sig(float x) {
  float e = EXP2F(-1.44269504f * x);
  return RCPF(1.0f + e);
}
__device__ __forceinline__ float fast_tanh(float x) {
  float e = EXP2F(2.88539008f * x);   // e^(2x)
  return 1.0f - 2.0f * RCPF(1.0f + e);
}

// XOR swizzle within a [16 rows][256B] tile: spreads a column's 16B units
// across bank groups. Applied identically at producer (global ring write),
// consumer LDS read, and h ping-pong write/read.
__device__ __forceinline__ int swz(int row, int byteInRow) {
  return (row * 256 + byteInRow) ^ ((row & 7) << 4);
}

// ---------------- prep: fp16 weights, combined bias, zero flags ----------------
__global__ __launch_bounds__(256) void prep_kernel(
    const float* __restrict__ Wih0, const float* __restrict__ Whh0,
    const float* __restrict__ bih,  const float* __restrict__ bhh,
    const float* __restrict__ Wih,  const float* __restrict__ Whh,
    _Float16* __restrict__ W0h, _Float16* __restrict__ Wc,
    float* __restrict__ biasc, unsigned* __restrict__ flags)
{
  long idx = (long)blockIdx.x * 256 + threadIdx.x;
  const long NWC = (long)NL * G4 * 256;   // 2,621,440
  const long NW0 = (long)G4 * EE;         // 393,216
  const long NBI = (long)NL * G4;         // 10,240
  if (idx < NWC) {
    int l = (int)(idx >> 17);
    int rem = (int)(idx & 131071);
    int n = rem >> 8, kk = rem & 255;
    float v;
    if (l == 0) v = (kk < 128) ? 0.0f : Whh0[n * H4 + kk - 128];
    else v = (kk < 128) ? Wih[((long)(l-1) * G4 + n) * H4 + kk]
                        : Whh[((long)(l-1) * G4 + n) * H4 + kk - 128];
    Wc[idx] = (_Float16)v;
  } else if ((idx -= NWC) < NW0) {
    W0h[idx] = (_Float16)Wih0[idx];
  } else if ((idx -= NW0) < NBI) {
    int l = (int)(idx >> 9), n = (int)(idx & 511);
    biasc[idx] = (l == 0) ? 0.0f : (bih[(l-1) * G4 + n] + bhh[(l-1) * G4 + n]);
  } else if ((idx -= NBI) < 256) {
    flags[idx] = 0u;
  }
}

// ---------------- layer-0 input projection GEMM: pre0[t][n][b] fp16 ----------------
__global__ __launch_bounds__(512) void pre0_gemm(
    const float* __restrict__ x, const _Float16* __restrict__ W0h,
    const float* __restrict__ bih0, const float* __restrict__ bhh0,
    _Float16* __restrict__ pre0)
{
  __shared__ __align__(16) unsigned char smem[46080];
  _Float16* sA = (_Float16*)smem;             // [64][40]
  _Float16* sB = (_Float16*)(smem + 5120);    // [512][40]
  _Float16* sC = (_Float16*)smem;             // alias: [256][72] bounce
  int t = blockIdx.x;
  int tid = threadIdx.x;
  int w = tid >> 6, lane = tid & 63;
  int l15 = lane & 15, kb = lane >> 4;

  v4f acc[4][4];
#pragma unroll
  for (int mi = 0; mi < 4; ++mi)
#pragma unroll
    for (int ni = 0; ni < 4; ++ni) acc[mi][ni] = (v4f){0.f, 0.f, 0.f, 0.f};

  int bA = tid >> 3, kqA = tid & 7;
  const float* xp = x + ((long)bA * TT + t) * EE + kqA * 4;
  const _Float16* wp = W0h + (long)tid * EE;

  for (int k0 = 0; k0 < EE; k0 += 32) {
    float4 xv = *(const float4*)(xp + k0);
    v4h xh = { (_Float16)xv.x, (_Float16)xv.y, (_Float16)xv.z, (_Float16)xv.w };
    *(v4h*)&sA[bA * 40 + kqA * 4] = xh;
#pragma unroll
    for (int c = 0; c < 4; ++c)
      *(v8h*)&sB[tid * 40 + c * 8] = *(const v8h*)(wp + k0 + c * 8);
    __syncthreads();
#pragma unroll
    for (int mi = 0; mi < 4; ++mi) {
      v8h a = *(const v8h*)&sA[(16 * mi + l15) * 40 + kb * 8];
#pragma unroll
      for (int ni = 0; ni < 4; ++ni) {
        v8h b = *(const v8h*)&sB[(64 * w + 16 * ni + l15) * 40 + kb * 8];
        acc[mi][ni] = __builtin_amdgcn_mfma_f32_16x16x32_f16(a, b, acc[mi][ni], 0, 0, 0);
      }
    }
    __syncthreads();
  }

#pragma unroll
  for (int hh2 = 0; hh2 < 2; ++hh2) {
    __syncthreads();
    if ((w >> 2) == hh2) {
      int wl = w & 3;
#pragma unroll
      for (int ni = 0; ni < 4; ++ni) {
        int nloc = 64 * wl + 16 * ni + l15;
        int n = 256 * hh2 + nloc;
        float bia = bih0[n] + bhh0[n];
#pragma unroll
        for (int mi = 0; mi < 4; ++mi)
#pragma unroll
          for (int r = 0; r < 4; ++r)
            sC[nloc * 72 + 16 * mi + 4 * kb + r] = (_Float16)(acc[mi][ni][r] + bia);
      }
    }
    __syncthreads();
    int row = tid >> 1, part = tid & 1;
    _Float16* po = pre0 + ((long)t * G4 + 256 * hh2 + row) * 64 + part * 32;
#pragma unroll
    for (int c = 0; c < 4; ++c)
      *(v8h*)(po + c * 8) = *(const v8h*)&sC[row * 72 + part * 32 + c * 8];
  }
}

// ---------------- persistent pipelined LSTM, chunked handoff ----------------
// 160 blocks (layer l, batch-group bg). 8 waves; wave w owns j-strip [16w,16w+16)
// for all 4 gates; weights truly VGPR-resident (launch_bounds(512,1) -> 256 regs).
// Cross-layer handoff every CK steps through an RC-chunk ring in LLC (sc0 sc1).
// Producer writes the ring PRE-SWIZZLED so the consumer's 32KB copy is linear.
__global__ __launch_bounds__(512, 1) void lstm_pipe(
    const _Float16* __restrict__ pre0, const _Float16* __restrict__ Wc,
    const float* __restrict__ biasc, _Float16* __restrict__ yring,
    unsigned* __restrict__ flags, float* __restrict__ out)
{
  // LDS: y chunk tile [CK][2048B] (swizzled rows) = 32KB, h ping-pong [2][4096B] = 8KB
  __shared__ __align__(16) unsigned char lds[40960];
  const int l = blockIdx.x >> 3, bg = blockIdx.x & 7;
  const int tid = threadIdx.x, w = tid >> 6, lane = tid & 63;
  const int l15 = lane & 15, kb = lane >> 4;
  const int jloc = 16 * w + l15;
  const bool valid = (kb < 2);
  const int b0 = 4 * (kb & 1);

  // weight fragments resident for the whole kernel (128 VGPRs)
  v8h bw[4][8];
  const _Float16* wbase = Wc + (long)l * G4 * 256;
#pragma unroll
  for (int q = 0; q < 4; ++q)
#pragma unroll
    for (int ks = 0; ks < 8; ++ks)
      bw[q][ks] = *(const v8h*)(wbase + (long)(128 * q + jloc) * 256 + ks * 32 + kb * 8);
  // pin the weight fragments in registers
#pragma unroll
  for (int q = 0; q < 4; ++q)
#pragma unroll
    for (int ks = 0; ks < 8; ++ks)
      asm volatile("" : "+v"(bw[q][ks]));

  float bias_q[4];
#pragma unroll
  for (int q = 0; q < 4; ++q)
    bias_q[q] = (l == 0) ? 0.0f : biasc[l * G4 + 128 * q + jloc];

  // zero h ping-pong buffers (512 threads x 16B = 8KB)
  *(v4u*)(lds + 32768 + tid * 16) = (v4u){0u, 0u, 0u, 0u};

  const int myf = l * 8 + bg;
  const unsigned* fin  = flags + ((l > 0) ? (myf - 8) : myf);
  const unsigned* fout = flags + ((l < NL - 1) ? (myf + 8) : myf);
  unsigned* fme = flags + myf;
  char* ywr = (char*)(yring + (long)myf * (RC * CK * 1024));
  const char* yrd = (const char*)(yring + (long)(myf - 8) * (RC * CK * 1024));

  v4f cst = (v4f){0.f, 0.f, 0.f, 0.f};
  v4h pc[4];
  if (l == 0) {
    const _Float16* pb = pre0 + bg * 8 + b0;
#pragma unroll
    for (int q = 0; q < 4; ++q)
      pc[q] = *(const v4h*)(pb + (long)(128 * q + jloc) * 64);
  }

  __syncthreads();

  for (int c = 0; c < NCH; ++c) {
    if (l > 0) {
      // wait for producer chunk c (LLC-coherent poll)
      unsigned f;
      for (;;) {
        asm volatile("global_load_dword %0, %1, off sc0 sc1\n\ts_waitcnt vmcnt(0)"
                     : "=v"(f) : "v"(fin));
        if (f > (unsigned)c) break;
        __builtin_amdgcn_s_sleep(2);
      }
      // linear 32KB bulk copy (ring already swizzled by producer)
      const char* src = yrd + (long)(c & (RC - 1)) * 32768 + tid * 16;
      v4u d0, d1, d2, d3;
      asm volatile("global_load_dwordx4 %0, %1, off sc0 sc1" : "=v"(d0) : "v"(src));
      asm volatile("global_load_dwordx4 %0, %1, off sc0 sc1" : "=v"(d1) : "v"(src + 8192));
      asm volatile("global_load_dwordx4 %0, %1, off sc0 sc1" : "=v"(d2) : "v"(src + 16384));
      asm volatile("global_load_dwordx4 %0, %1, off sc0 sc1" : "=v"(d3) : "v"(src + 24576));
      asm volatile("s_waitcnt vmcnt(0)" ::: "memory");
      __builtin_amdgcn_sched_barrier(0);
      unsigned char* dst = lds + tid * 16;
      *(v4u*)(dst)         = d0;
      *(v4u*)(dst +  8192) = d1;
      *(v4u*)(dst + 16384) = d2;
      *(v4u*)(dst + 24576) = d3;
    }
    if (l < NL - 1 && c >= RC) {
      // backpressure: ring slot (c mod RC) must be consumed
      unsigned f;
      for (;;) {
        asm volatile("global_load_dword %0, %1, off sc0 sc1\n\ts_waitcnt vmcnt(0)"
                     : "=v"(f) : "v"(fout));
        if (f >= (unsigned)(c - 1)) break;
        __builtin_amdgcn_s_sleep(2);
      }
    }
    __syncthreads();

    for (int ts = 0; ts < CK; ++ts) {
      const int t = c * CK + ts;
      const int p = t & 1;
      v4f acc[4];
#pragma unroll
      for (int q = 0; q < 4; ++q)
        acc[q] = (v4f){bias_q[q], bias_q[q], bias_q[q], bias_q[q]};

      v4h pn[4];
      if (l == 0) {
#pragma unroll
        for (int q = 0; q < 4; ++q)
#pragma unroll
          for (int r = 0; r < 4; ++r) acc[q][r] += (float)pc[q][r];
        // prefetch next step's pre0 (hides LLC latency under this step)
        const int tn = (t + 1) & (TT - 1);
        const _Float16* pb = pre0 + (long)tn * G4 * 64 + bg * 8 + b0;
#pragma unroll
        for (int q = 0; q < 4; ++q)
          pn[q] = *(const v4h*)(pb + (long)(128 * q + jloc) * 64);
      }

      const unsigned char* hb = lds + 32768 + p * 4096;
      if (l > 0) {
        const unsigned char* yb = lds + ts * 2048;
#pragma unroll
        for (int ks = 0; ks < 4; ++ks) {
          v8h a = *(const v8h*)(yb + swz(l15, ks * 64 + kb * 16));
#pragma unroll
          for (int q = 0; q < 4; ++q)
            acc[q] = __builtin_amdgcn_mfma_f32_16x16x32_f16(a, bw[q][ks], acc[q], 0, 0, 0);
        }
      }
#pragma unroll
      for (int ks = 4; ks < 8; ++ks) {
        v8h a = *(const v8h*)(hb + swz(l15, (ks - 4) * 64 + kb * 16));
#pragma unroll
        for (int q = 0; q < 4; ++q)
          acc[q] = __builtin_amdgcn_mfma_f32_16x16x32_f16(a, bw[q][ks], acc[q], 0, 0, 0);
      }

      _Float16 hh[4]; float hf[4];
#pragma unroll
      for (int r = 0; r < 4; ++r) {
        float i_ = fast_sig(acc[0][r]);
        float f_ = fast_sig(acc[1][r]);
        float g_ = fast_tanh(acc[2][r]);
        float o_ = fast_sig(acc[3][r]);
        float cn = f_ * cst[r] + i_ * g_;
        cst[r] = cn;
        float h_ = o_ * fast_tanh(cn);
        hf[r] = h_; hh[r] = (_Float16)h_;
      }

      if (valid) {
        unsigned char* hn = lds + 32768 + (p ^ 1) * 4096;
#pragma unroll
        for (int r = 0; r < 4; ++r)
          *(_Float16*)(hn + swz(b0 + r, jloc * 2)) = hh[r];
        if (l < NL - 1) {
          // pre-swizzled ring store: 4 x 2B at swz(b, j*2)
          char* dstb = ywr + (long)(c & (RC - 1)) * 32768 + ts * 2048;
#pragma unroll
          for (int r = 0; r < 4; ++r) {
            union { _Float16 h; unsigned short u; } cv; cv.h = hh[r];
            unsigned val = cv.u;
            char* dst = dstb + swz(b0 + r, jloc * 2);
            asm volatile("global_store_short %0, %1, off sc0 sc1"
                         :: "v"(dst), "v"(val) : "memory");
          }
        } else if (t == TT - 1) {
#pragma unroll
          for (int r = 0; r < 4; ++r)
            out[(bg * 8 + b0 + r) * H4 + jloc] = hf[r];
        }
      }
      if (l == 0) {
#pragma unroll
        for (int q = 0; q < 4; ++q) pc[q] = pn[q];
      }
      __syncthreads();
    }

    // publish chunk c (stores drained on every wave before flag)
    asm volatile("s_waitcnt vmcnt(0)" ::: "memory");
    __syncthreads();
    if (tid == 0) {
      unsigned v = (unsigned)(c + 1);
      asm volatile("global_store_dword %0, %1, off sc0 sc1" :: "v"(fme), "v"(v) : "memory");
    }
  }
}

extern "C" void kernel_launch(void* const* d_in, const int* in_sizes, int n_in,
                              void* d_out, int out_size, void* d_ws, size_t ws_size,
                              hipStream_t stream)
{
  const float* x    = (const float*)d_in[0];
  const float* Wih0 = (const float*)d_in[1];
  const float* Whh0 = (const float*)d_in[2];
  const float* bih0 = (const float*)d_in[3];
  const float* bhh0 = (const float*)d_in[4];
  const float* Wih  = (const float*)d_in[5];
  const float* Whh  = (const float*)d_in[6];
  const float* bih  = (const float*)d_in[7];
  const float* bhh  = (const float*)d_in[8];
  float* out = (float*)d_out;
  char* ws = (char*)d_ws;

  _Float16* pre0  = (_Float16*)(ws);              // 33,554,432 B
  _Float16* W0h   = (_Float16*)(ws + 33554432);   //    786,432 B
  _Float16* Wc    = (_Float16*)(ws + 34340864);   //  5,242,880 B
  float*    bc    = (float*)   (ws + 39583744);   //     40,960 B
  _Float16* yring = (_Float16*)(ws + 39624704);   // 10,485,760 B
  unsigned* flags = (unsigned*)(ws + 50110464);   //      1,024 B

  prep_kernel<<<11817, 256, 0, stream>>>(Wih0, Whh0, bih, bhh, Wih, Whh, W0h, Wc, bc, flags);
  pre0_gemm<<<TT, 512, 0, stream>>>(x, W0h, bih0, bhh0, pre0);
  lstm_pipe<<<NL * NBG, 512, 0, stream>>>(pre0, Wc, bc, yring, flags, out);
}

// Round 4
// 1101.413 us; speedup vs baseline: 1.0720x; 1.0720x over previous
//
#include <hip/hip_runtime.h>

#define H4 128     // hidden
#define EE 768     // embedding
#define NL 20      // layers
#define BB 64      // batch
#define TT 512     // seq len
#define G4 512     // 4*H
#define NBG 8      // batch groups
#define CK 16      // timesteps per chunk (handoff granularity)
#define NCH (TT/CK)
#define RC 2       // ring slots (chunks) per flow

typedef _Float16 v8h __attribute__((ext_vector_type(8)));
typedef _Float16 v4h __attribute__((ext_vector_type(4)));
typedef float v4f __attribute__((ext_vector_type(4)));
typedef unsigned int v4u __attribute__((ext_vector_type(4)));

#if defined(__has_builtin)
#if __has_builtin(__builtin_amdgcn_exp2f) && __has_builtin(__builtin_amdgcn_rcpf)
#define EXP2F __builtin_amdgcn_exp2f
#define RCPF  __builtin_amdgcn_rcpf
#endif
#endif
#ifndef EXP2F
#define EXP2F exp2f
#define RCPF(x) (1.0f/(x))
#endif

__device__ __forceinline__ float fast_sig(float x) {
  float e = EXP2F(-1.44269504f * x);
  return RCPF(1.0f + e);
}
__device__ __forceinline__ float fast_tanh(float x) {
  float e = EXP2F(2.88539008f * x);   // e^(2x)
  return 1.0f - 2.0f * RCPF(1.0f + e);
}

// XOR swizzle within a [16 rows][256B] tile: spreads a column's 16B units
// across bank groups. XOR touches only bits 4..6 -> stays within the row.
__device__ __forceinline__ int swz(int row, int byteInRow) {
  return (row * 256 + byteInRow) ^ ((row & 7) << 4);
}

// ---------------- prep: fp16 weights, combined bias, zero flags ----------------
__global__ __launch_bounds__(256) void prep_kernel(
    const float* __restrict__ Wih0, const float* __restrict__ Whh0,
    const float* __restrict__ bih,  const float* __restrict__ bhh,
    const float* __restrict__ Wih,  const float* __restrict__ Whh,
    _Float16* __restrict__ W0h, _Float16* __restrict__ Wc,
    float* __restrict__ biasc, unsigned* __restrict__ flags)
{
  long idx = (long)blockIdx.x * 256 + threadIdx.x;
  const long NWC = (long)NL * G4 * 256;   // 2,621,440
  const long NW0 = (long)G4 * EE;         // 393,216
  const long NBI = (long)NL * G4;         // 10,240
  if (idx < NWC) {
    int l = (int)(idx >> 17);
    int rem = (int)(idx & 131071);
    int n = rem >> 8, kk = rem & 255;
    float v;
    if (l == 0) v = (kk < 128) ? 0.0f : Whh0[n * H4 + kk - 128];
    else v = (kk < 128) ? Wih[((long)(l-1) * G4 + n) * H4 + kk]
                        : Whh[((long)(l-1) * G4 + n) * H4 + kk - 128];
    Wc[idx] = (_Float16)v;
  } else if ((idx -= NWC) < NW0) {
    W0h[idx] = (_Float16)Wih0[idx];
  } else if ((idx -= NW0) < NBI) {
    int l = (int)(idx >> 9), n = (int)(idx & 511);
    biasc[idx] = (l == 0) ? 0.0f : (bih[(l-1) * G4 + n] + bhh[(l-1) * G4 + n]);
  } else if ((idx -= NBI) < 256) {
    flags[idx] = 0u;
  }
}

// ---------------- layer-0 input projection GEMM ----------------
// pre0 layout: [t][bg(8)][n(512)][b8(8)] fp16 -> per (t,bg) an 8KB contiguous block,
// so lstm_pipe's layer-0 reads are coalesced.
__global__ __launch_bounds__(512) void pre0_gemm(
    const float* __restrict__ x, const _Float16* __restrict__ W0h,
    const float* __restrict__ bih0, const float* __restrict__ bhh0,
    _Float16* __restrict__ pre0)
{
  __shared__ __align__(16) unsigned char smem[46080];
  _Float16* sA = (_Float16*)smem;             // [64][40]
  _Float16* sB = (_Float16*)(smem + 5120);    // [512][40]
  _Float16* sC = (_Float16*)smem;             // alias: [256][72] bounce
  int t = blockIdx.x;
  int tid = threadIdx.x;
  int w = tid >> 6, lane = tid & 63;
  int l15 = lane & 15, kb = lane >> 4;

  v4f acc[4][4];
#pragma unroll
  for (int mi = 0; mi < 4; ++mi)
#pragma unroll
    for (int ni = 0; ni < 4; ++ni) acc[mi][ni] = (v4f){0.f, 0.f, 0.f, 0.f};

  int bA = tid >> 3, kqA = tid & 7;
  const float* xp = x + ((long)bA * TT + t) * EE + kqA * 4;
  const _Float16* wp = W0h + (long)tid * EE;

  for (int k0 = 0; k0 < EE; k0 += 32) {
    float4 xv = *(const float4*)(xp + k0);
    v4h xh = { (_Float16)xv.x, (_Float16)xv.y, (_Float16)xv.z, (_Float16)xv.w };
    *(v4h*)&sA[bA * 40 + kqA * 4] = xh;
#pragma unroll
    for (int c = 0; c < 4; ++c)
      *(v8h*)&sB[tid * 40 + c * 8] = *(const v8h*)(wp + k0 + c * 8);
    __syncthreads();
#pragma unroll
    for (int mi = 0; mi < 4; ++mi) {
      v8h a = *(const v8h*)&sA[(16 * mi + l15) * 40 + kb * 8];
#pragma unroll
      for (int ni = 0; ni < 4; ++ni) {
        v8h b = *(const v8h*)&sB[(64 * w + 16 * ni + l15) * 40 + kb * 8];
        acc[mi][ni] = __builtin_amdgcn_mfma_f32_16x16x32_f16(a, b, acc[mi][ni], 0, 0, 0);
      }
    }
    __syncthreads();
  }

#pragma unroll
  for (int hh2 = 0; hh2 < 2; ++hh2) {
    __syncthreads();
    if ((w >> 2) == hh2) {
      int wl = w & 3;
#pragma unroll
      for (int ni = 0; ni < 4; ++ni) {
        int nloc = 64 * wl + 16 * ni + l15;
        int n = 256 * hh2 + nloc;
        float bia = bih0[n] + bhh0[n];
#pragma unroll
        for (int mi = 0; mi < 4; ++mi)
#pragma unroll
          for (int r = 0; r < 4; ++r)
            sC[nloc * 72 + 16 * mi + 4 * kb + r] = (_Float16)(acc[mi][ni][r] + bia);
      }
    }
    __syncthreads();
    int row = tid >> 1, part = tid & 1;    // row: n-local 0..255, part: b-half
    int n = 256 * hh2 + row;
#pragma unroll
    for (int g = 0; g < 4; ++g) {
      int bg = part * 4 + g;
      _Float16* po = pre0 + (((long)t * 8 + bg) * 512 + n) * 8;
      *(v8h*)po = *(const v8h*)&sC[row * 72 + part * 32 + g * 8];
    }
  }
}

// ---------------- persistent pipelined LSTM, chunked handoff ----------------
// 160 blocks (layer l, batch-group bg). 8 waves; wave w owns j-strip [16w,16w+16)
// for all 4 gates; weight fragments resident (AGPR/VGPR unified file).
// Cross-layer handoff every CK steps through an RC-chunk ring in LLC (sc0 sc1).
// Ring image is the swizzled LDS image -> all ring traffic is fully coalesced:
// producer copies LDS->ring 1 dword/thread/step, consumer copies ring->LDS 64B/thread/chunk.
__global__ __launch_bounds__(512, 1) void lstm_pipe(
    const _Float16* __restrict__ pre0, const _Float16* __restrict__ Wc,
    const float* __restrict__ biasc, _Float16* __restrict__ yring,
    unsigned* __restrict__ flags, float* __restrict__ out)
{
  // LDS: y chunk tile [CK][2048B] (swizzled rows) = 32KB, h ping-pong [2][4096B] = 8KB
  __shared__ __align__(16) unsigned char lds[40960];
  const int l = blockIdx.x >> 3, bg = blockIdx.x & 7;
  const int tid = threadIdx.x, w = tid >> 6, lane = tid & 63;
  const int l15 = lane & 15, kb = lane >> 4;
  const int jloc = 16 * w + l15;
  const bool valid = (kb < 2);
  const int b0 = 4 * (kb & 1);

  // weight fragments resident for the whole kernel (unified VGPR/AGPR file)
  v8h bw[4][8];
  const _Float16* wbase = Wc + (long)l * G4 * 256;
#pragma unroll
  for (int q = 0; q < 4; ++q)
#pragma unroll
    for (int ks = 0; ks < 8; ++ks)
      bw[q][ks] = *(const v8h*)(wbase + (long)(128 * q + jloc) * 256 + ks * 32 + kb * 8);

  float bias_q[4];
#pragma unroll
  for (int q = 0; q < 4; ++q)
    bias_q[q] = (l == 0) ? 0.0f : biasc[l * G4 + 128 * q + jloc];

  // zero h ping-pong buffers (512 threads x 16B = 8KB)
  *(v4u*)(lds + 32768 + tid * 16) = (v4u){0u, 0u, 0u, 0u};

  const int myf = l * 8 + bg;
  const unsigned* fin  = flags + ((l > 0) ? (myf - 8) : myf);
  const unsigned* fout = flags + ((l < NL - 1) ? (myf + 8) : myf);
  unsigned* fme = flags + myf;
  char* ywr = (char*)(yring + (long)myf * (RC * CK * 1024));
  const char* yrd = (const char*)(yring + (long)(myf - 8) * (RC * CK * 1024));

  v4f cst = (v4f){0.f, 0.f, 0.f, 0.f};
  v4h pc[4];
  const _Float16* pbase0 = pre0 + (long)bg * 4096 + jloc * 8 + b0;
  if (l == 0) {
#pragma unroll
    for (int q = 0; q < 4; ++q)
      pc[q] = *(const v4h*)(pbase0 + q * 1024);
  }

  __syncthreads();

  for (int c = 0; c < NCH; ++c) {
    if (l > 0) {
      // wait for producer chunk c (LLC-coherent poll)
      unsigned f;
      for (;;) {
        asm volatile("global_load_dword %0, %1, off sc0 sc1\n\ts_waitcnt vmcnt(0)"
                     : "=v"(f) : "v"(fin));
        if (f > (unsigned)c) break;
        __builtin_amdgcn_s_sleep(2);
      }
      // linear 32KB bulk copy (ring already holds the swizzled LDS image)
      const char* src = yrd + (long)(c & (RC - 1)) * 32768 + tid * 16;
      v4u d0, d1, d2, d3;
      asm volatile("global_load_dwordx4 %0, %1, off sc0 sc1" : "=v"(d0) : "v"(src));
      asm volatile("global_load_dwordx4 %0, %1, off sc0 sc1" : "=v"(d1) : "v"(src + 8192));
      asm volatile("global_load_dwordx4 %0, %1, off sc0 sc1" : "=v"(d2) : "v"(src + 16384));
      asm volatile("global_load_dwordx4 %0, %1, off sc0 sc1" : "=v"(d3) : "v"(src + 24576));
      asm volatile("s_waitcnt vmcnt(0)" ::: "memory");
      __builtin_amdgcn_sched_barrier(0);
      unsigned char* dst = lds + tid * 16;
      *(v4u*)(dst)         = d0;
      *(v4u*)(dst +  8192) = d1;
      *(v4u*)(dst + 16384) = d2;
      *(v4u*)(dst + 24576) = d3;
    }
    if (l < NL - 1 && c >= RC) {
      // backpressure: ring slot (c mod RC) must be consumed
      unsigned f;
      for (;;) {
        asm volatile("global_load_dword %0, %1, off sc0 sc1\n\ts_waitcnt vmcnt(0)"
                     : "=v"(f) : "v"(fout));
        if (f >= (unsigned)(c - 1)) break;
        __builtin_amdgcn_s_sleep(2);
      }
    }
    __syncthreads();

    for (int ts = 0; ts < CK; ++ts) {
      const int t = c * CK + ts;
      const int p = t & 1;
      v4f acc[4];
#pragma unroll
      for (int q = 0; q < 4; ++q)
        acc[q] = (v4f){bias_q[q], bias_q[q], bias_q[q], bias_q[q]};

      v4h pn[4];
      if (l == 0) {
#pragma unroll
        for (int q = 0; q < 4; ++q)
#pragma unroll
          for (int r = 0; r < 4; ++r) acc[q][r] += (float)pc[q][r];
        // prefetch next step's pre0 (hides L2/LLC latency under this step)
        const int tn = (t + 1) & (TT - 1);
        const _Float16* pb = pbase0 + (long)tn * 32768;
#pragma unroll
        for (int q = 0; q < 4; ++q)
          pn[q] = *(const v4h*)(pb + q * 1024);
      }

      const unsigned char* hb = lds + 32768 + p * 4096;
      if (l > 0) {
        const unsigned char* yb = lds + ts * 2048;
#pragma unroll
        for (int ks = 0; ks < 4; ++ks) {
          v8h a = *(const v8h*)(yb + swz(l15, ks * 64 + kb * 16));
#pragma unroll
          for (int q = 0; q < 4; ++q)
            acc[q] = __builtin_amdgcn_mfma_f32_16x16x32_f16(a, bw[q][ks], acc[q], 0, 0, 0);
        }
      }
#pragma unroll
      for (int ks = 4; ks < 8; ++ks) {
        v8h a = *(const v8h*)(hb + swz(l15, (ks - 4) * 64 + kb * 16));
#pragma unroll
        for (int q = 0; q < 4; ++q)
          acc[q] = __builtin_amdgcn_mfma_f32_16x16x32_f16(a, bw[q][ks], acc[q], 0, 0, 0);
      }

      _Float16 hh[4]; float hf[4];
#pragma unroll
      for (int r = 0; r < 4; ++r) {
        float i_ = fast_sig(acc[0][r]);
        float f_ = fast_sig(acc[1][r]);
        float g_ = fast_tanh(acc[2][r]);
        float o_ = fast_sig(acc[3][r]);
        float cn = f_ * cst[r] + i_ * g_;
        cst[r] = cn;
        float h_ = o_ * fast_tanh(cn);
        hf[r] = h_; hh[r] = (_Float16)h_;
      }

      if (valid) {
        unsigned char* hn = lds + 32768 + (p ^ 1) * 4096;
#pragma unroll
        for (int r = 0; r < 4; ++r)
          *(_Float16*)(hn + swz(b0 + r, jloc * 2)) = hh[r];
        if (l == NL - 1 && t == TT - 1) {
#pragma unroll
          for (int r = 0; r < 4; ++r)
            out[(bg * 8 + b0 + r) * H4 + jloc] = hf[r];
        }
      }
      if (l == 0) {
#pragma unroll
        for (int q = 0; q < 4; ++q) pc[q] = pn[q];
      }
      __syncthreads();

      // coalesced ring store: copy the just-completed h slot (2KB, swizzled
      // image, rows 0-7) to the ring — 1 dword per thread, fire-and-forget.
      if (l < NL - 1) {
        unsigned hv = *(const unsigned*)(lds + 32768 + (p ^ 1) * 4096 + tid * 4);
        char* dst = ywr + (long)(c & (RC - 1)) * 32768 + ts * 2048 + tid * 4;
        asm volatile("global_store_dword %0, %1, off sc0 sc1"
                     :: "v"(dst), "v"(hv) : "memory");
      }
    }

    // publish chunk c (stores drained on every wave before flag)
    asm volatile("s_waitcnt vmcnt(0)" ::: "memory");
    __syncthreads();
    if (tid == 0) {
      unsigned v = (unsigned)(c + 1);
      asm volatile("global_store_dword %0, %1, off sc0 sc1" :: "v"(fme), "v"(v) : "memory");
    }
  }
}

extern "C" void kernel_launch(void* const* d_in, const int* in_sizes, int n_in,
                              void* d_out, int out_size, void* d_ws, size_t ws_size,
                              hipStream_t stream)
{
  const float* x    = (const float*)d_in[0];
  const float* Wih0 = (const float*)d_in[1];
  const float* Whh0 = (const float*)d_in[2];
  const float* bih0 = (const float*)d_in[3];
  const float* bhh0 = (const float*)d_in[4];
  const float* Wih  = (const float*)d_in[5];
  const float* Whh  = (const float*)d_in[6];
  const float* bih  = (const float*)d_in[7];
  const float* bhh  = (const float*)d_in[8];
  float* out = (float*)d_out;
  char* ws = (char*)d_ws;

  _Float16* pre0  = (_Float16*)(ws);              // 33,554,432 B
  _Float16* W0h   = (_Float16*)(ws + 33554432);   //    786,432 B
  _Float16* Wc    = (_Float16*)(ws + 34340864);   //  5,242,880 B
  float*    bc    = (float*)   (ws + 39583744);   //     40,960 B
  _Float16* yring = (_Float16*)(ws + 39624704);   // 10,485,760 B
  unsigned* flags = (unsigned*)(ws + 50110464);   //      1,024 B

  prep_kernel<<<11817, 256, 0, stream>>>(Wih0, Whh0, bih, bhh, Wih, Whh, W0h, Wc, bc, flags);
  pre0_gemm<<<TT, 512, 0, stream>>>(x, W0h, bih0, bhh0, pre0);
  lstm_pipe<<<NL * NBG, 512, 0, stream>>>(pre0, Wc, bc, yring, flags, out);
}

// Round 5
// 1072.418 us; speedup vs baseline: 1.1010x; 1.0270x over previous
//
#include <hip/hip_runtime.h>

#define H4 128     // hidden
#define EE 768     // embedding
#define NL 20      // layers
#define BB 64      // batch
#define TT 512     // seq len
#define G4 512     // 4*H
#define NBG 8      // batch groups
#define CK 16      // timesteps per chunk (handoff granularity)
#define NCH (TT/CK)
#define RC 2       // ring slots (chunks) per flow
#define HB 131072  // LDS byte offset of h ping-pong region

typedef _Float16 v8h __attribute__((ext_vector_type(8)));
typedef _Float16 v4h __attribute__((ext_vector_type(4)));
typedef float v4f __attribute__((ext_vector_type(4)));
typedef unsigned int v4u __attribute__((ext_vector_type(4)));

#if defined(__has_builtin)
#if __has_builtin(__builtin_amdgcn_exp2f) && __has_builtin(__builtin_amdgcn_rcpf)
#define EXP2F __builtin_amdgcn_exp2f
#define RCPF  __builtin_amdgcn_rcpf
#endif
#endif
#ifndef EXP2F
#define EXP2F exp2f
#define RCPF(x) (1.0f/(x))
#endif

__device__ __forceinline__ float fast_sig(float x) {
  float e = EXP2F(-1.44269504f * x);
  return RCPF(1.0f + e);
}
__device__ __forceinline__ float fast_tanh(float x) {
  float e = EXP2F(2.88539008f * x);   // e^(2x)
  return 1.0f - 2.0f * RCPF(1.0f + e);
}

// XOR swizzle within a [16 rows][256B] tile.
__device__ __forceinline__ int swz(int row, int byteInRow) {
  return (row * 256 + byteInRow) ^ ((row & 7) << 4);
}

// ---------------- prep: fp16 weights, combined bias, zero flags ----------------
__global__ __launch_bounds__(256) void prep_kernel(
    const float* __restrict__ Wih0, const float* __restrict__ Whh0,
    const float* __restrict__ bih,  const float* __restrict__ bhh,
    const float* __restrict__ Wih,  const float* __restrict__ Whh,
    _Float16* __restrict__ W0h, _Float16* __restrict__ Wc,
    float* __restrict__ biasc, unsigned* __restrict__ flags)
{
  long idx = (long)blockIdx.x * 256 + threadIdx.x;
  const long NWC = (long)NL * G4 * 256;   // 2,621,440
  const long NW0 = (long)G4 * EE;         // 393,216
  const long NBI = (long)NL * G4;         // 10,240
  if (idx < NWC) {
    int l = (int)(idx >> 17);
    int rem = (int)(idx & 131071);
    int n = rem >> 8, kk = rem & 255;
    float v;
    if (l == 0) v = (kk < 128) ? 0.0f : Whh0[n * H4 + kk - 128];
    else v = (kk < 128) ? Wih[((long)(l-1) * G4 + n) * H4 + kk]
                        : Whh[((long)(l-1) * G4 + n) * H4 + kk - 128];
    Wc[idx] = (_Float16)v;
  } else if ((idx -= NWC) < NW0) {
    W0h[idx] = (_Float16)Wih0[idx];
  } else if ((idx -= NW0) < NBI) {
    int l = (int)(idx >> 9), n = (int)(idx & 511);
    biasc[idx] = (l == 0) ? 0.0f : (bih[(l-1) * G4 + n] + bhh[(l-1) * G4 + n]);
  } else if ((idx -= NBI) < 256) {
    flags[idx] = 0u;
  }
}

// ---------------- layer-0 input projection GEMM ----------------
// pre0 layout: [t][bg(8)][n(512)][b8(8)] fp16 -> per (t,bg) an 8KB contiguous block.
__global__ __launch_bounds__(512) void pre0_gemm(
    const float* __restrict__ x, const _Float16* __restrict__ W0h,
    const float* __restrict__ bih0, const float* __restrict__ bhh0,
    _Float16* __restrict__ pre0)
{
  __shared__ __align__(16) unsigned char smem[46080];
  _Float16* sA = (_Float16*)smem;             // [64][40]
  _Float16* sB = (_Float16*)(smem + 5120);    // [512][40]
  _Float16* sC = (_Float16*)smem;             // alias: [256][72] bounce
  int t = blockIdx.x;
  int tid = threadIdx.x;
  int w = tid >> 6, lane = tid & 63;
  int l15 = lane & 15, kb = lane >> 4;

  v4f acc[4][4];
#pragma unroll
  for (int mi = 0; mi < 4; ++mi)
#pragma unroll
    for (int ni = 0; ni < 4; ++ni) acc[mi][ni] = (v4f){0.f, 0.f, 0.f, 0.f};

  int bA = tid >> 3, kqA = tid & 7;
  const float* xp = x + ((long)bA * TT + t) * EE + kqA * 4;
  const _Float16* wp = W0h + (long)tid * EE;

  for (int k0 = 0; k0 < EE; k0 += 32) {
    float4 xv = *(const float4*)(xp + k0);
    v4h xh = { (_Float16)xv.x, (_Float16)xv.y, (_Float16)xv.z, (_Float16)xv.w };
    *(v4h*)&sA[bA * 40 + kqA * 4] = xh;
#pragma unroll
    for (int c = 0; c < 4; ++c)
      *(v8h*)&sB[tid * 40 + c * 8] = *(const v8h*)(wp + k0 + c * 8);
    __syncthreads();
#pragma unroll
    for (int mi = 0; mi < 4; ++mi) {
      v8h a = *(const v8h*)&sA[(16 * mi + l15) * 40 + kb * 8];
#pragma unroll
      for (int ni = 0; ni < 4; ++ni) {
        v8h b = *(const v8h*)&sB[(64 * w + 16 * ni + l15) * 40 + kb * 8];
        acc[mi][ni] = __builtin_amdgcn_mfma_f32_16x16x32_f16(a, b, acc[mi][ni], 0, 0, 0);
      }
    }
    __syncthreads();
  }

#pragma unroll
  for (int hh2 = 0; hh2 < 2; ++hh2) {
    __syncthreads();
    if ((w >> 2) == hh2) {
      int wl = w & 3;
#pragma unroll
      for (int ni = 0; ni < 4; ++ni) {
        int nloc = 64 * wl + 16 * ni + l15;
        int n = 256 * hh2 + nloc;
        float bia = bih0[n] + bhh0[n];
#pragma unroll
        for (int mi = 0; mi < 4; ++mi)
#pragma unroll
          for (int r = 0; r < 4; ++r)
            sC[nloc * 72 + 16 * mi + 4 * kb + r] = (_Float16)(acc[mi][ni][r] + bia);
      }
    }
    __syncthreads();
    int row = tid >> 1, part = tid & 1;    // row: n-local 0..255, part: b-half
    int n = 256 * hh2 + row;
#pragma unroll
    for (int g = 0; g < 4; ++g) {
      int bg = part * 4 + g;
      _Float16* po = pre0 + (((long)t * 8 + bg) * 512 + n) * 8;
      *(v8h*)po = *(const v8h*)&sC[row * 72 + part * 32 + g * 8];
    }
  }
}

// ---------------- persistent pipelined LSTM, chunked handoff ----------------
// 160 blocks (layer l, batch-group bg). 8 waves; wave w owns j-strip [16w,16w+16)
// for all 4 gates; weight fragments register-resident. Per-step sync is raw
// s_barrier + lgkmcnt(0) ONLY — no per-step vmcnt drain. Device-scope ring
// stores stay in flight across the whole chunk; one vmcnt(0) before publish.
// LDS: [0,128K) = l==0 ? pre-gate chunk [16ts][8KB] : y-tile [16ts][2KB];
//      [128K,136K) = h ping-pong 2 x 4KB.
__global__ __launch_bounds__(512, 1) void lstm_pipe(
    const _Float16* __restrict__ pre0, const _Float16* __restrict__ Wc,
    const float* __restrict__ biasc, _Float16* __restrict__ yring,
    unsigned* __restrict__ flags, float* __restrict__ out)
{
  __shared__ __align__(16) unsigned char lds[HB + 8192];
  const int l = blockIdx.x >> 3, bg = blockIdx.x & 7;
  const int tid = threadIdx.x, w = tid >> 6, lane = tid & 63;
  const int l15 = lane & 15, kb = lane >> 4;
  const int jloc = 16 * w + l15;
  const bool valid = (kb < 2);
  const int b0 = 4 * (kb & 1);

  // weight fragments resident for the whole kernel
  v8h bw[4][8];
  const _Float16* wbase = Wc + (long)l * G4 * 256;
#pragma unroll
  for (int q = 0; q < 4; ++q)
#pragma unroll
    for (int ks = 0; ks < 8; ++ks)
      bw[q][ks] = *(const v8h*)(wbase + (long)(128 * q + jloc) * 256 + ks * 32 + kb * 8);

  float bias_q[4];
#pragma unroll
  for (int q = 0; q < 4; ++q)
    bias_q[q] = (l == 0) ? 0.0f : biasc[l * G4 + 128 * q + jloc];

  // zero h ping-pong buffers (512 threads x 16B = 8KB)
  *(v4u*)(lds + HB + tid * 16) = (v4u){0u, 0u, 0u, 0u};

  const int myf = l * 8 + bg;
  const unsigned* fin  = flags + ((l > 0) ? (myf - 8) : myf);
  const unsigned* fout = flags + ((l < NL - 1) ? (myf + 8) : myf);
  unsigned* fme = flags + myf;
  char* ywr = (char*)(yring + (long)myf * (RC * CK * 1024));
  const char* yrd = (const char*)(yring + (long)(myf - 8) * (RC * CK * 1024));
  const char* pre0b = (const char*)pre0;

  v4f cst = (v4f){0.f, 0.f, 0.f, 0.f};

  __syncthreads();   // one-time init barrier (vmcnt drain OK here)

  for (int c = 0; c < NCH; ++c) {
    if (l > 0) {
      // wait for producer chunk c (LLC-coherent poll)
      unsigned f;
      for (;;) {
        asm volatile("global_load_dword %0, %1, off sc0 sc1\n\ts_waitcnt vmcnt(0)"
                     : "=v"(f) : "v"(fin));
        if (f > (unsigned)c) break;
        __builtin_amdgcn_s_sleep(2);
      }
      // linear 32KB bulk copy (ring holds the swizzled LDS image)
      const char* src = yrd + (long)(c & (RC - 1)) * 32768 + tid * 16;
      v4u d0, d1, d2, d3;
      asm volatile("global_load_dwordx4 %0, %1, off sc0 sc1" : "=v"(d0) : "v"(src));
      asm volatile("global_load_dwordx4 %0, %1, off sc0 sc1" : "=v"(d1) : "v"(src + 8192));
      asm volatile("global_load_dwordx4 %0, %1, off sc0 sc1" : "=v"(d2) : "v"(src + 16384));
      asm volatile("global_load_dwordx4 %0, %1, off sc0 sc1" : "=v"(d3) : "v"(src + 24576));
      asm volatile("s_waitcnt vmcnt(0)" ::: "memory");
      __builtin_amdgcn_sched_barrier(0);
      unsigned char* dst = lds + tid * 16;
      *(v4u*)(dst)         = d0;
      *(v4u*)(dst +  8192) = d1;
      *(v4u*)(dst + 16384) = d2;
      *(v4u*)(dst + 24576) = d3;
    } else {
      // layer 0: stage the whole chunk's pre-gates (16 x 8KB = 128KB) into LDS
      v4u d[16];
#pragma unroll
      for (int ts = 0; ts < CK; ++ts) {
        const char* s = pre0b + ((long)(c * CK + ts) * 8 + bg) * 8192 + tid * 16;
        d[ts] = *(const v4u*)s;
      }
#pragma unroll
      for (int ts = 0; ts < CK; ++ts)
        *(v4u*)(lds + ts * 8192 + tid * 16) = d[ts];
    }
    if (l < NL - 1 && c >= RC) {
      // backpressure: ring slot (c mod RC) must be consumed
      unsigned f;
      for (;;) {
        asm volatile("global_load_dword %0, %1, off sc0 sc1\n\ts_waitcnt vmcnt(0)"
                     : "=v"(f) : "v"(fout));
        if (f >= (unsigned)(c - 1)) break;
        __builtin_amdgcn_s_sleep(2);
      }
    }
    asm volatile("s_waitcnt lgkmcnt(0)" ::: "memory");
    __builtin_amdgcn_s_barrier();
    __builtin_amdgcn_sched_barrier(0);

    for (int ts = 0; ts < CK; ++ts) {
      const int t = c * CK + ts;
      const int p = t & 1;
      v4f acc[4];
#pragma unroll
      for (int q = 0; q < 4; ++q)
        acc[q] = (v4f){bias_q[q], bias_q[q], bias_q[q], bias_q[q]};

      const unsigned char* hb = lds + HB + p * 4096;
      if (l == 0) {
        // lane-private pre-gate add from LDS (conflict-free b64 reads)
        const unsigned char* pbts = lds + ts * 8192 + (kb & 1) * 8;
#pragma unroll
        for (int q = 0; q < 4; ++q) {
          v4h pv = *(const v4h*)(pbts + (128 * q + jloc) * 16);
#pragma unroll
          for (int r = 0; r < 4; ++r) acc[q][r] += (float)pv[r];
        }
      } else {
        const unsigned char* yb = lds + ts * 2048;
#pragma unroll
        for (int ks = 0; ks < 4; ++ks) {
          v8h a = *(const v8h*)(yb + swz(l15, ks * 64 + kb * 16));
#pragma unroll
          for (int q = 0; q < 4; ++q)
            acc[q] = __builtin_amdgcn_mfma_f32_16x16x32_f16(a, bw[q][ks], acc[q], 0, 0, 0);
        }
      }
#pragma unroll
      for (int ks = 4; ks < 8; ++ks) {
        v8h a = *(const v8h*)(hb + swz(l15, (ks - 4) * 64 + kb * 16));
#pragma unroll
        for (int q = 0; q < 4; ++q)
          acc[q] = __builtin_amdgcn_mfma_f32_16x16x32_f16(a, bw[q][ks], acc[q], 0, 0, 0);
      }

      _Float16 hh[4]; float hf[4];
#pragma unroll
      for (int r = 0; r < 4; ++r) {
        float i_ = fast_sig(acc[0][r]);
        float f_ = fast_sig(acc[1][r]);
        float g_ = fast_tanh(acc[2][r]);
        float o_ = fast_sig(acc[3][r]);
        float cn = f_ * cst[r] + i_ * g_;
        cst[r] = cn;
        float h_ = o_ * fast_tanh(cn);
        hf[r] = h_; hh[r] = (_Float16)h_;
      }

      if (valid) {
        unsigned char* hn = lds + HB + (p ^ 1) * 4096;
#pragma unroll
        for (int r = 0; r < 4; ++r)
          *(_Float16*)(hn + swz(b0 + r, jloc * 2)) = hh[r];
        if (l == NL - 1 && t == TT - 1) {
#pragma unroll
          for (int r = 0; r < 4; ++r)
            out[(bg * 8 + b0 + r) * H4 + jloc] = hf[r];
        }
      }

      // step barrier: LDS-only wait, NO vmcnt drain
      asm volatile("s_waitcnt lgkmcnt(0)" ::: "memory");
      __builtin_amdgcn_s_barrier();
      __builtin_amdgcn_sched_barrier(0);

      // coalesced ring store of the just-completed h slot (fire-and-forget,
      // stays in flight across steps; drained once at chunk end)
      if (l < NL - 1) {
        unsigned hv = *(const unsigned*)(lds + HB + (p ^ 1) * 4096 + tid * 4);
        char* dst = ywr + (long)(c & (RC - 1)) * 32768 + ts * 2048 + tid * 4;
        asm volatile("global_store_dword %0, %1, off sc0 sc1" :: "v"(dst), "v"(hv));
      }
    }

    // publish chunk c (all waves drain their ring stores, then one flag store)
    asm volatile("s_waitcnt vmcnt(0)" ::: "memory");
    __builtin_amdgcn_s_barrier();
    __builtin_amdgcn_sched_barrier(0);
    if (tid == 0) {
      unsigned v = (unsigned)(c + 1);
      asm volatile("global_store_dword %0, %1, off sc0 sc1" :: "v"(fme), "v"(v) : "memory");
    }
  }
}

extern "C" void kernel_launch(void* const* d_in, const int* in_sizes, int n_in,
                              void* d_out, int out_size, void* d_ws, size_t ws_size,
                              hipStream_t stream)
{
  const float* x    = (const float*)d_in[0];
  const float* Wih0 = (const float*)d_in[1];
  const float* Whh0 = (const float*)d_in[2];
  const float* bih0 = (const float*)d_in[3];
  const float* bhh0 = (const float*)d_in[4];
  const float* Wih  = (const float*)d_in[5];
  const float* Whh  = (const float*)d_in[6];
  const float* bih  = (const float*)d_in[7];
  const float* bhh  = (const float*)d_in[8];
  float* out = (float*)d_out;
  char* ws = (char*)d_ws;

  _Float16* pre0  = (_Float16*)(ws);              // 33,554,432 B
  _Float16* W0h   = (_Float16*)(ws + 33554432);   //    786,432 B
  _Float16* Wc    = (_Float16*)(ws + 34340864);   //  5,242,880 B
  float*    bc    = (float*)   (ws + 39583744);   //     40,960 B
  _Float16* yring = (_Float16*)(ws + 39624704);   // 10,485,760 B
  unsigned* flags = (unsigned*)(ws + 50110464);   //      1,024 B

  prep_kernel<<<11817, 256, 0, stream>>>(Wih0, Whh0, bih, bhh, Wih, Whh, W0h, Wc, bc, flags);
  pre0_gemm<<<TT, 512, 0, stream>>>(x, W0h, bih0, bhh0, pre0);
  lstm_pipe<<<NL * NBG, 512, 0, stream>>>(pre0, Wc, bc, yring, flags, out);
}

// Round 6
// 978.553 us; speedup vs baseline: 1.2066x; 1.0959x over previous
//
#include <hip/hip_runtime.h>

#define H4 128     // hidden
#define EE 768     // embedding
#define NL 20      // layers
#define BB 64      // batch
#define TT 512     // seq len
#define G4 512     // 4*H
#define NBG 8      // batch groups
#define CK 8       // timesteps per chunk (handoff granularity)
#define NCH (TT/CK)
#define RC 4       // ring slots (chunks) per flow
#define HB 65536   // LDS byte offset of h ping-pong region

typedef _Float16 v8h __attribute__((ext_vector_type(8)));
typedef _Float16 v4h __attribute__((ext_vector_type(4)));
typedef float v4f __attribute__((ext_vector_type(4)));
typedef unsigned int v4u __attribute__((ext_vector_type(4)));

#if defined(__has_builtin)
#if __has_builtin(__builtin_amdgcn_exp2f) && __has_builtin(__builtin_amdgcn_rcpf)
#define EXP2F __builtin_amdgcn_exp2f
#define RCPF  __builtin_amdgcn_rcpf
#endif
#endif
#ifndef EXP2F
#define EXP2F exp2f
#define RCPF(x) (1.0f/(x))
#endif

__device__ __forceinline__ float fast_sig(float x) {
  float e = EXP2F(-1.44269504f * x);
  return RCPF(1.0f + e);
}
__device__ __forceinline__ float fast_tanh(float x) {
  float e = EXP2F(2.88539008f * x);   // e^(2x)
  return 1.0f - 2.0f * RCPF(1.0f + e);
}

// XOR swizzle within a [16 rows][256B] tile.
__device__ __forceinline__ int swz(int row, int byteInRow) {
  return (row * 256 + byteInRow) ^ ((row & 7) << 4);
}

// ---------------- prep: fp16 weights, combined bias, zero flags ----------------
__global__ __launch_bounds__(256) void prep_kernel(
    const float* __restrict__ Wih0, const float* __restrict__ Whh0,
    const float* __restrict__ bih,  const float* __restrict__ bhh,
    const float* __restrict__ Wih,  const float* __restrict__ Whh,
    _Float16* __restrict__ W0h, _Float16* __restrict__ Wc,
    float* __restrict__ biasc, unsigned* __restrict__ flags)
{
  long idx = (long)blockIdx.x * 256 + threadIdx.x;
  const long NWC = (long)NL * G4 * 256;   // 2,621,440
  const long NW0 = (long)G4 * EE;         // 393,216
  const long NBI = (long)NL * G4;         // 10,240
  if (idx < NWC) {
    int l = (int)(idx >> 17);
    int rem = (int)(idx & 131071);
    int n = rem >> 8, kk = rem & 255;
    float v;
    if (l == 0) v = (kk < 128) ? 0.0f : Whh0[n * H4 + kk - 128];
    else v = (kk < 128) ? Wih[((long)(l-1) * G4 + n) * H4 + kk]
                        : Whh[((long)(l-1) * G4 + n) * H4 + kk - 128];
    Wc[idx] = (_Float16)v;
  } else if ((idx -= NWC) < NW0) {
    W0h[idx] = (_Float16)Wih0[idx];
  } else if ((idx -= NW0) < NBI) {
    int l = (int)(idx >> 9), n = (int)(idx & 511);
    biasc[idx] = (l == 0) ? 0.0f : (bih[(l-1) * G4 + n] + bhh[(l-1) * G4 + n]);
  } else if ((idx -= NBI) < 256) {
    flags[idx] = 0u;
  }
}

// ---------------- layer-0 input projection GEMM ----------------
// pre0 layout: [t][bg(8)][n(512)][b8(8)] fp16 -> per (t,bg) an 8KB contiguous block.
__global__ __launch_bounds__(512) void pre0_gemm(
    const float* __restrict__ x, const _Float16* __restrict__ W0h,
    const float* __restrict__ bih0, const float* __restrict__ bhh0,
    _Float16* __restrict__ pre0)
{
  __shared__ __align__(16) unsigned char smem[46080];
  _Float16* sA = (_Float16*)smem;             // [64][40]
  _Float16* sB = (_Float16*)(smem + 5120);    // [512][40]
  _Float16* sC = (_Float16*)smem;             // alias: [256][72] bounce
  int t = blockIdx.x;
  int tid = threadIdx.x;
  int w = tid >> 6, lane = tid & 63;
  int l15 = lane & 15, kb = lane >> 4;

  v4f acc[4][4];
#pragma unroll
  for (int mi = 0; mi < 4; ++mi)
#pragma unroll
    for (int ni = 0; ni < 4; ++ni) acc[mi][ni] = (v4f){0.f, 0.f, 0.f, 0.f};

  int bA = tid >> 3, kqA = tid & 7;
  const float* xp = x + ((long)bA * TT + t) * EE + kqA * 4;
  const _Float16* wp = W0h + (long)tid * EE;

  for (int k0 = 0; k0 < EE; k0 += 32) {
    float4 xv = *(const float4*)(xp + k0);
    v4h xh = { (_Float16)xv.x, (_Float16)xv.y, (_Float16)xv.z, (_Float16)xv.w };
    *(v4h*)&sA[bA * 40 + kqA * 4] = xh;
#pragma unroll
    for (int c = 0; c < 4; ++c)
      *(v8h*)&sB[tid * 40 + c * 8] = *(const v8h*)(wp + k0 + c * 8);
    __syncthreads();
#pragma unroll
    for (int mi = 0; mi < 4; ++mi) {
      v8h a = *(const v8h*)&sA[(16 * mi + l15) * 40 + kb * 8];
#pragma unroll
      for (int ni = 0; ni < 4; ++ni) {
        v8h b = *(const v8h*)&sB[(64 * w + 16 * ni + l15) * 40 + kb * 8];
        acc[mi][ni] = __builtin_amdgcn_mfma_f32_16x16x32_f16(a, b, acc[mi][ni], 0, 0, 0);
      }
    }
    __syncthreads();
  }

#pragma unroll
  for (int hh2 = 0; hh2 < 2; ++hh2) {
    __syncthreads();
    if ((w >> 2) == hh2) {
      int wl = w & 3;
#pragma unroll
      for (int ni = 0; ni < 4; ++ni) {
        int nloc = 64 * wl + 16 * ni + l15;
        int n = 256 * hh2 + nloc;
        float bia = bih0[n] + bhh0[n];
#pragma unroll
        for (int mi = 0; mi < 4; ++mi)
#pragma unroll
          for (int r = 0; r < 4; ++r)
            sC[nloc * 72 + 16 * mi + 4 * kb + r] = (_Float16)(acc[mi][ni][r] + bia);
      }
    }
    __syncthreads();
    int row = tid >> 1, part = tid & 1;    // row: n-local 0..255, part: b-half
    int n = 256 * hh2 + row;
#pragma unroll
    for (int g = 0; g < 4; ++g) {
      int bg = part * 4 + g;
      _Float16* po = pre0 + (((long)t * 8 + bg) * 512 + n) * 8;
      *(v8h*)po = *(const v8h*)&sC[row * 72 + part * 32 + g * 8];
    }
  }
}

// ---------------- persistent pipelined LSTM ----------------
// 160 blocks (layer l, batch-group bg). 8 waves; wave w owns j-strip [16w,16w+16).
// Step recurrence: [barrier] -> h ds_read -> 16 MFMA h-chains (4-deep) ->
// combine with pre-barrier y-chains -> shfl repack (all 64 lanes) -> gates ->
// h write -> prefetch+MFMA next step's y-part -> [barrier].
// LDS: [0,16K) y-tile (l>0) / [0,64K) pre-tile (l==0); [64K,72K) h ping-pong.
__global__ __launch_bounds__(512, 1) void lstm_pipe(
    const _Float16* __restrict__ pre0, const _Float16* __restrict__ Wc,
    const float* __restrict__ biasc, _Float16* __restrict__ yring,
    unsigned* __restrict__ flags, float* __restrict__ out)
{
  __shared__ __align__(16) unsigned char lds[HB + 8192];
  const int l = blockIdx.x >> 3, bg = blockIdx.x & 7;
  const int tid = threadIdx.x, w = tid >> 6, lane = tid & 63;
  const int l15 = lane & 15, kb = lane >> 4;
  const int jloc = 16 * w + l15;
  const bool lo = (kb < 2);
  const int rp = (kb & 1) * 2 + (kb >> 1);   // row-pair: rows 2rp, 2rp+1 after repack

  // weight fragments resident for the whole kernel
  v8h bw[4][8];
  const _Float16* wbase = Wc + (long)l * G4 * 256;
#pragma unroll
  for (int q = 0; q < 4; ++q)
#pragma unroll
    for (int ks = 0; ks < 8; ++ks)
      bw[q][ks] = *(const v8h*)(wbase + (long)(128 * q + jloc) * 256 + ks * 32 + kb * 8);

  float bias_q[4];
#pragma unroll
  for (int q = 0; q < 4; ++q)
    bias_q[q] = (l == 0) ? 0.0f : biasc[l * G4 + 128 * q + jloc];

  // zero h ping-pong buffers
  *(v4u*)(lds + HB + tid * 16) = (v4u){0u, 0u, 0u, 0u};

  const int myf = l * 8 + bg;
  const unsigned* fin  = flags + ((l > 0) ? (myf - 8) : myf);
  const unsigned* fout = flags + ((l < NL - 1) ? (myf + 8) : myf);
  unsigned* fme = flags + myf;
  char* ywr = (char*)(yring + (long)myf * (RC * CK * 1024));
  const char* yrd = (const char*)(yring + (long)(myf - 8) * (RC * CK * 1024));
  const char* pre0b = (const char*)pre0;

  float c0 = 0.f, c1 = 0.f;

  __syncthreads();

  for (int c = 0; c < NCH; ++c) {
    if (l > 0) {
      unsigned f;
      for (;;) {
        asm volatile("global_load_dword %0, %1, off sc0 sc1\n\ts_waitcnt vmcnt(0)"
                     : "=v"(f) : "v"(fin));
        if (f > (unsigned)c) break;
        __builtin_amdgcn_s_sleep(2);
      }
      // linear 16KB bulk copy (ring holds the swizzled LDS image)
      const char* src = yrd + (long)(c & (RC - 1)) * (CK * 2048) + tid * 32;
      v4u d0, d1;
      asm volatile("global_load_dwordx4 %0, %1, off sc0 sc1" : "=v"(d0) : "v"(src));
      asm volatile("global_load_dwordx4 %0, %1, off sc0 sc1" : "=v"(d1) : "v"(src + 16));
      asm volatile("s_waitcnt vmcnt(0)" ::: "memory");
      __builtin_amdgcn_sched_barrier(0);
      *(v4u*)(lds + tid * 32)      = d0;
      *(v4u*)(lds + tid * 32 + 16) = d1;
    } else {
      // layer 0: stage chunk's pre-gates (8 x 8KB = 64KB) into LDS
      v4u d[CK];
#pragma unroll
      for (int ts = 0; ts < CK; ++ts) {
        const char* s = pre0b + ((long)(c * CK + ts) * 8 + bg) * 8192 + tid * 16;
        d[ts] = *(const v4u*)s;
      }
#pragma unroll
      for (int ts = 0; ts < CK; ++ts)
        *(v4u*)(lds + ts * 8192 + tid * 16) = d[ts];
    }
    if (l < NL - 1 && c >= RC) {
      unsigned f;
      for (;;) {
        asm volatile("global_load_dword %0, %1, off sc0 sc1\n\ts_waitcnt vmcnt(0)"
                     : "=v"(f) : "v"(fout));
        if (f >= (unsigned)(c - RC + 1)) break;
        __builtin_amdgcn_s_sleep(2);
      }
    }
    asm volatile("s_waitcnt lgkmcnt(0)" ::: "memory");
    __builtin_amdgcn_s_barrier();
    __builtin_amdgcn_sched_barrier(0);

    // prologue: ts=0 h-independent operands (+ y MFMA for l>0)
    v8h yf[4];
    unsigned pr[4];
    v4f accA[4];
    if (l > 0) {
#pragma unroll
      for (int ks = 0; ks < 4; ++ks)
        yf[ks] = *(const v8h*)(lds + swz(l15, ks * 64 + kb * 16));
#pragma unroll
      for (int q = 0; q < 4; ++q) {
        accA[q] = (v4f){bias_q[q], bias_q[q], bias_q[q], bias_q[q]};
#pragma unroll
        for (int ks = 0; ks < 4; ++ks)
          accA[q] = __builtin_amdgcn_mfma_f32_16x16x32_f16(yf[ks], bw[q][ks], accA[q], 0, 0, 0);
      }
    } else {
#pragma unroll
      for (int q = 0; q < 4; ++q)
        pr[q] = *(const unsigned*)(lds + (128 * q + jloc) * 16 + rp * 4);
    }

    for (int ts = 0; ts < CK; ++ts) {
      const int t = c * CK + ts;
      const int p = t & 1;
      const unsigned char* hb = lds + HB + p * 4096;

      // h-part MFMA (critical path after barrier)
      v4f accB[4];
#pragma unroll
      for (int q = 0; q < 4; ++q) accB[q] = (v4f){0.f, 0.f, 0.f, 0.f};
#pragma unroll
      for (int ks = 0; ks < 4; ++ks) {
        v8h hf = *(const v8h*)(hb + swz(l15, ks * 64 + kb * 16));
#pragma unroll
        for (int q = 0; q < 4; ++q)
          accB[q] = __builtin_amdgcn_mfma_f32_16x16x32_f16(hf, bw[q][ks + 4], accB[q], 0, 0, 0);
      }

      // combine + repack across the full wave (2 elements per lane)
      float w0[4], w1[4];
#pragma unroll
      for (int q = 0; q < 4; ++q) {
        v4f s = (l > 0) ? (accA[q] + accB[q]) : accB[q];
        float t2 = __shfl_xor(s[2], 32);
        float t3 = __shfl_xor(s[3], 32);
        w0[q] = lo ? s[0] : t2;
        w1[q] = lo ? s[1] : t3;
      }
      if (l == 0) {
#pragma unroll
        for (int q = 0; q < 4; ++q) {
          union { unsigned u; _Float16 h[2]; } uu; uu.u = pr[q];
          w0[q] += (float)uu.h[0];
          w1[q] += (float)uu.h[1];
        }
      }

      // gates (all 64 lanes, 2 elements each)
      float i0 = fast_sig(w0[0]), ff0 = fast_sig(w0[1]);
      float g0 = fast_tanh(w0[2]), o0 = fast_sig(w0[3]);
      c0 = ff0 * c0 + i0 * g0;
      float h0 = o0 * fast_tanh(c0);
      float i1 = fast_sig(w1[0]), ff1 = fast_sig(w1[1]);
      float g1 = fast_tanh(w1[2]), o1 = fast_sig(w1[3]);
      c1 = ff1 * c1 + i1 * g1;
      float h1 = o1 * fast_tanh(c1);

      // write h (2 x b16 per lane)
      unsigned char* hn = lds + HB + (p ^ 1) * 4096;
      *(_Float16*)(hn + swz(2 * rp,     jloc * 2)) = (_Float16)h0;
      *(_Float16*)(hn + swz(2 * rp + 1, jloc * 2)) = (_Float16)h1;
      if (l == NL - 1 && t == TT - 1) {
        out[(bg * 8 + 2 * rp) * H4 + jloc]     = h0;
        out[(bg * 8 + 2 * rp + 1) * H4 + jloc] = h1;
      }

      // prefetch next step's h-independent operands; l>0 also runs its y-MFMAs
      // BEFORE the barrier (overlaps other waves' gate phase)
      if (ts < CK - 1) {
        if (l > 0) {
          const unsigned char* yb = lds + (ts + 1) * 2048;
#pragma unroll
          for (int ks = 0; ks < 4; ++ks)
            yf[ks] = *(const v8h*)(yb + swz(l15, ks * 64 + kb * 16));
#pragma unroll
          for (int q = 0; q < 4; ++q) {
            accA[q] = (v4f){bias_q[q], bias_q[q], bias_q[q], bias_q[q]};
#pragma unroll
            for (int ks = 0; ks < 4; ++ks)
              accA[q] = __builtin_amdgcn_mfma_f32_16x16x32_f16(yf[ks], bw[q][ks], accA[q], 0, 0, 0);
          }
        } else {
          const unsigned char* pb = lds + (ts + 1) * 8192;
#pragma unroll
          for (int q = 0; q < 4; ++q)
            pr[q] = *(const unsigned*)(pb + (128 * q + jloc) * 16 + rp * 4);
        }
      }

      asm volatile("s_waitcnt lgkmcnt(0)" ::: "memory");
      __builtin_amdgcn_sched_barrier(0);
      __builtin_amdgcn_s_barrier();
      __builtin_amdgcn_sched_barrier(0);

      // coalesced ring store of the just-completed h slot (fire-and-forget)
      if (l < NL - 1) {
        unsigned hv = *(const unsigned*)(lds + HB + (p ^ 1) * 4096 + tid * 4);
        char* dst = ywr + (long)(c & (RC - 1)) * (CK * 2048) + ts * 2048 + tid * 4;
        asm volatile("global_store_dword %0, %1, off sc0 sc1" :: "v"(dst), "v"(hv));
      }
    }

    // publish chunk c
    asm volatile("s_waitcnt vmcnt(0)" ::: "memory");
    __builtin_amdgcn_s_barrier();
    __builtin_amdgcn_sched_barrier(0);
    if (tid == 0) {
      unsigned v = (unsigned)(c + 1);
      asm volatile("global_store_dword %0, %1, off sc0 sc1" :: "v"(fme), "v"(v) : "memory");
    }
  }
}

extern "C" void kernel_launch(void* const* d_in, const int* in_sizes, int n_in,
                              void* d_out, int out_size, void* d_ws, size_t ws_size,
                              hipStream_t stream)
{
  const float* x    = (const float*)d_in[0];
  const float* Wih0 = (const float*)d_in[1];
  const float* Whh0 = (const float*)d_in[2];
  const float* bih0 = (const float*)d_in[3];
  const float* bhh0 = (const float*)d_in[4];
  const float* Wih  = (const float*)d_in[5];
  const float* Whh  = (const float*)d_in[6];
  const float* bih  = (const float*)d_in[7];
  const float* bhh  = (const float*)d_in[8];
  float* out = (float*)d_out;
  char* ws = (char*)d_ws;

  _Float16* pre0  = (_Float16*)(ws);              // 33,554,432 B
  _Float16* W0h   = (_Float16*)(ws + 33554432);   //    786,432 B
  _Float16* Wc    = (_Float16*)(ws + 34340864);   //  5,242,880 B
  float*    bc    = (float*)   (ws + 39583744);   //     40,960 B
  _Float16* yring = (_Float16*)(ws + 39624704);   // 10,485,760 B (160 x RC x CK x 1024 x 2B)
  unsigned* flags = (unsigned*)(ws + 50110464);   //      1,024 B

  prep_kernel<<<11817, 256, 0, stream>>>(Wih0, Whh0, bih, bhh, Wih, Whh, W0h, Wc, bc, flags);
  pre0_gemm<<<TT, 512, 0, stream>>>(x, W0h, bih0, bhh0, pre0);
  lstm_pipe<<<NL * NBG, 512, 0, stream>>>(pre0, Wc, bc, yring, flags, out);
}